// Round 1
// baseline (443.648 us; speedup 1.0000x reference)
//
#include <hip/hip_runtime.h>
#include <hip/hip_bf16.h>

// Problem dims (fixed)
#define B_   16
#define T_   1024
#define R_   16
#define NP_  64
#define N_   1024      // R_*NP_
#define NL_  20
#define NC_  32
#define H_   256
#define RNL  320       // R_*NL_
#define RNC  512       // R_*NC_

// ws layout (float offsets)
#define OFF_WCOMB 0
#define OFF_BCOMB (OFF_WCOMB + N_*H_)            // 262144
#define OFF_AMAT  (OFF_BCOMB + H_)               // 262400
#define OFF_CVEC  (OFF_AMAT + N_*RNL)            // 590080
#define OFF_LAT   (OFF_CVEC + RNL)               // 590400
#define OFF_ACC   (OFF_LAT + (size_t)B_*T_*RNL)  // 5833280  (+2) ≈ 23.3 MB total

__global__ void k_init(float* acc) {
    if (threadIdx.x < 2) acc[threadIdx.x] = 0.f;
}

// W_comb[row=r*64+n][h] = keep[r] * sum_c W_stitch[r][n][c] * W_U[r*32+c][h]
__global__ __launch_bounds__(256) void k_comb(const float* __restrict__ Wst,
                                              const float* __restrict__ Wu,
                                              const int* __restrict__ keep,
                                              float* __restrict__ Wcomb) {
    const int g = blockIdx.x * 256 + threadIdx.x;   // 262144 total
    const int row = g >> 8, h = g & 255;
    const int r = row >> 6;
    const float* ws = Wst + (size_t)row * NC_;      // W_stitch[r][n][*]
    const float* wu = Wu + (size_t)(r * NC_) * H_ + h;
    float acc = 0.f;
#pragma unroll
    for (int c = 0; c < NC_; ++c) acc = fmaf(ws[c], wu[c * H_], acc);
    Wcomb[g] = keep[r] ? acc : 0.f;
}

// b_comb[h] = b_U[h] + sum_{kept rc} b_stitch[rc] * W_U[rc][h]
__global__ void k_bcomb(const float* __restrict__ bst, const float* __restrict__ Wu,
                        const float* __restrict__ bu, const int* __restrict__ keep,
                        float* __restrict__ bcomb) {
    const int h = threadIdx.x;  // 256
    float acc = bu[h];
    for (int rc = 0; rc < RNC; ++rc)
        if (keep[rc >> 5]) acc = fmaf(bst[rc], Wu[(size_t)rc * H_ + h], acc);
    bcomb[h] = acc;
}

// c[j] = b_V[j] + sum_h b_comb[h] * W_V[h][j]
__global__ void k_cvec(const float* __restrict__ bcomb, const float* __restrict__ Wv,
                       const float* __restrict__ bv, float* __restrict__ cvec) {
    const int j = threadIdx.x;  // 320
    float acc = bv[j];
    for (int h = 0; h < H_; ++h) acc = fmaf(bcomb[h], Wv[(size_t)h * RNL + j], acc);
    cvec[j] = acc;
}

// Row-major C[M][N] = A[M][K] @ Bm[K][N] (+ bias[N]). BM=128 BN=64 BK=16, 256 thr, 8x4 micro.
__global__ __launch_bounds__(256) void gemm_bias(const float* __restrict__ A,
                                                 const float* __restrict__ Bm,
                                                 const float* __restrict__ bias,
                                                 float* __restrict__ C,
                                                 int M, int N, int K) {
    __shared__ float As[16][132];   // [k][m], padded: stores 2-way, reads conflict-free
    __shared__ float Bs[16][64];    // [k][n]
    const int tid = threadIdx.x;
    const int bm = blockIdx.y * 128;
    const int bn = blockIdx.x * 64;
    const int tx = tid & 15, ty = tid >> 4;

    float acc[8][4];
#pragma unroll
    for (int i = 0; i < 8; ++i)
#pragma unroll
        for (int j = 0; j < 4; ++j) acc[i][j] = 0.f;

    for (int k0 = 0; k0 < K; k0 += 16) {
        // A tile: 128 rows x 16 k = 512 float4, 2 per thread (transposed into LDS)
#pragma unroll
        for (int i = 0; i < 2; ++i) {
            const int idx = tid + i * 256;
            const int r = idx >> 2, kq = (idx & 3) << 2;
            const float4 v = *reinterpret_cast<const float4*>(
                A + (size_t)(bm + r) * K + k0 + kq);
            As[kq + 0][r] = v.x; As[kq + 1][r] = v.y;
            As[kq + 2][r] = v.z; As[kq + 3][r] = v.w;
        }
        // B tile: 16 rows x 64 cols = 256 float4, 1 per thread
        {
            const int kr = tid >> 4, nq = (tid & 15) << 2;
            *reinterpret_cast<float4*>(&Bs[kr][nq]) =
                *reinterpret_cast<const float4*>(Bm + (size_t)(k0 + kr) * N + bn + nq);
        }
        __syncthreads();
#pragma unroll
        for (int k = 0; k < 16; ++k) {
            float a[8], b[4];
            *reinterpret_cast<float4*>(&a[0]) = *reinterpret_cast<const float4*>(&As[k][ty * 8]);
            *reinterpret_cast<float4*>(&a[4]) = *reinterpret_cast<const float4*>(&As[k][ty * 8 + 4]);
            *reinterpret_cast<float4*>(&b[0]) = *reinterpret_cast<const float4*>(&Bs[k][tx * 4]);
#pragma unroll
            for (int i = 0; i < 8; ++i)
#pragma unroll
                for (int j = 0; j < 4; ++j) acc[i][j] = fmaf(a[i], b[j], acc[i][j]);
        }
        __syncthreads();
    }
    float bv[4] = {0.f, 0.f, 0.f, 0.f};
    if (bias) {
        const float4 t = *reinterpret_cast<const float4*>(bias + bn + tx * 4);
        bv[0] = t.x; bv[1] = t.y; bv[2] = t.z; bv[3] = t.w;
    }
#pragma unroll
    for (int i = 0; i < 8; ++i) {
        float4 o;
        o.x = acc[i][0] + bv[0]; o.y = acc[i][1] + bv[1];
        o.z = acc[i][2] + bv[2]; o.w = acc[i][3] + bv[3];
        *reinterpret_cast<float4*>(C + (size_t)(bm + ty * 8 + i) * N + bn + tx * 4) = o;
    }
}

// preds = lat_r @ W_dec + b_dec (block-diag 20->64 per region), fused Poisson-NLL partial sum.
// One block handles 8 consecutive (b,t) rows. 256 threads; thread owns 4 consecutive n.
__global__ __launch_bounds__(256) void k_pred(const float* __restrict__ lat,
                                              const float* __restrict__ Wd,
                                              const float* __restrict__ bd,
                                              const float* __restrict__ tgt,
                                              float* __restrict__ preds,
                                              float* __restrict__ acc) {
    __shared__ float ls[8 * RNL];
    const int tid = threadIdx.x;
    const int bt0 = blockIdx.x * 8;  // over B_*T_
    const float* latrow = lat + (size_t)bt0 * RNL;
    for (int i = tid; i < 8 * RNL; i += 256) ls[i] = latrow[i];
    __syncthreads();

    const int n0 = tid * 4;
    const int r = n0 >> 6;
    const int nn = n0 & 63;
    float4 w[NL_];
#pragma unroll
    for (int l = 0; l < NL_; ++l)
        w[l] = *reinterpret_cast<const float4*>(Wd + ((size_t)(r * NL_ + l)) * NP_ + nn);
    const float4 bb = *reinterpret_cast<const float4*>(bd + r * NP_ + nn);

    float lsum = 0.f;
#pragma unroll
    for (int tt = 0; tt < 8; ++tt) {
        float p0 = bb.x, p1 = bb.y, p2 = bb.z, p3 = bb.w;
        const float* lr = &ls[tt * RNL + r * NL_];
#pragma unroll
        for (int l = 0; l < NL_; ++l) {
            const float lv = lr[l];
            p0 = fmaf(lv, w[l].x, p0); p1 = fmaf(lv, w[l].y, p1);
            p2 = fmaf(lv, w[l].z, p2); p3 = fmaf(lv, w[l].w, p3);
        }
        const size_t idx = (size_t)(bt0 + tt) * N_ + n0;
        const float4 tg = *reinterpret_cast<const float4*>(tgt + idx);
        float4 o; o.x = p0; o.y = p1; o.z = p2; o.w = p3;
        *reinterpret_cast<float4*>(preds + idx) = o;
        lsum += (__expf(p0) - tg.x * p0) + (__expf(p1) - tg.y * p1)
              + (__expf(p2) - tg.z * p2) + (__expf(p3) - tg.w * p3);
    }
#pragma unroll
    for (int off = 32; off; off >>= 1) lsum += __shfl_down(lsum, off);
    __shared__ float red[4];
    if ((tid & 63) == 0) red[tid >> 6] = lsum;
    __syncthreads();
    if (tid == 0) atomicAdd(acc, red[0] + red[1] + red[2] + red[3]);
}

// reg partial: sum |lat[b,t+1,j]-lat[b,t,j]|
__global__ __launch_bounds__(256) void k_reg(const float* __restrict__ lat,
                                             float* __restrict__ acc) {
    const int total = B_ * (T_ - 1) * RNL;  // 5237760
    float s = 0.f;
    for (int idx = blockIdx.x * 256 + threadIdx.x; idx < total; idx += gridDim.x * 256) {
        const int j = idx % RNL;
        const int rem = idx / RNL;
        const int t = rem % (T_ - 1);
        const int b = rem / (T_ - 1);
        const size_t o = ((size_t)(b * T_ + t)) * RNL + j;
        s += fabsf(lat[o + RNL] - lat[o]);
    }
#pragma unroll
    for (int off = 32; off; off >>= 1) s += __shfl_down(s, off);
    __shared__ float red[4];
    if ((threadIdx.x & 63) == 0) red[threadIdx.x >> 6] = s;
    __syncthreads();
    if (threadIdx.x == 0) atomicAdd(acc + 1, red[0] + red[1] + red[2] + red[3]);
}

__global__ void k_fin(const float* __restrict__ acc, float* __restrict__ out) {
    if (threadIdx.x == 0) {
        out[0] = acc[0] * (1.0f / ((float)B_ * T_ * N_));
        out[1] = acc[1] * (0.1f / ((float)B_ * (T_ - 1) * RNL));
    }
}

extern "C" void kernel_launch(void* const* d_in, const int* in_sizes, int n_in,
                              void* d_out, int out_size, void* d_ws, size_t ws_size,
                              hipStream_t stream) {
    const float* spikes = (const float*)d_in[0];
    // d_in[1] = neuron_regions (contiguous layout, unused)
    const int*   keep   = (const int*)d_in[2];
    const float* Wst    = (const float*)d_in[3];
    const float* bst    = (const float*)d_in[4];
    const float* Wu     = (const float*)d_in[5];
    const float* bu     = (const float*)d_in[6];
    const float* Wv     = (const float*)d_in[7];
    const float* bv     = (const float*)d_in[8];
    const float* Wd     = (const float*)d_in[9];
    const float* bd     = (const float*)d_in[10];
    float* out = (float*)d_out;
    float* ws  = (float*)d_ws;

    float* Wcomb = ws + OFF_WCOMB;
    float* bcomb = ws + OFF_BCOMB;
    float* Amat  = ws + OFF_AMAT;
    float* cvec  = ws + OFF_CVEC;
    float* lat   = ws + OFF_LAT;
    float* acc   = ws + OFF_ACC;

    k_init<<<1, 64, 0, stream>>>(acc);
    k_comb<<<(N_ * H_) / 256, 256, 0, stream>>>(Wst, Wu, keep, Wcomb);
    k_bcomb<<<1, 256, 0, stream>>>(bst, Wu, bu, keep, bcomb);
    k_cvec<<<1, RNL, 0, stream>>>(bcomb, Wv, bv, cvec);
    // Amat = Wcomb @ Wv  (1024x320, K=256)
    gemm_bias<<<dim3(RNL / 64, N_ / 128), 256, 0, stream>>>(Wcomb, Wv, nullptr, Amat,
                                                            N_, RNL, H_);
    // lat = spikes @ Amat + cvec  (16384x320, K=1024)
    gemm_bias<<<dim3(RNL / 64, (B_ * T_) / 128), 256, 0, stream>>>(spikes, Amat, cvec, lat,
                                                                   B_ * T_, RNL, N_);
    k_pred<<<(B_ * T_) / 8, 256, 0, stream>>>(lat, Wd, bd, spikes, out + 2, acc);
    k_reg<<<2048, 256, 0, stream>>>(lat, acc);
    k_fin<<<1, 64, 0, stream>>>(acc, out);
}

// Round 4
// 332.317 us; speedup vs baseline: 1.3350x; 1.3350x over previous
//
#include <hip/hip_runtime.h>
#include <hip/hip_bf16.h>

// Problem dims (fixed)
#define B_   16
#define T_   1024
#define R_   16
#define NP_  64
#define N_   1024      // R_*NP_
#define NL_  20
#define NC_  32
#define H_   256
#define RNL  320       // R_*NL_
#define RNC  512       // R_*NC_
#define BT_  (B_*T_)   // 16384

typedef __attribute__((ext_vector_type(8))) short bf16x8;
typedef __attribute__((ext_vector_type(4))) float f32x4;

// ws layout (float offsets)
#define OFF_WCOMB 0
#define OFF_BCOMB (OFF_WCOMB + N_*H_)            // 262144
#define OFF_AMAT  (OFF_BCOMB + H_)               // fp32 Amat [K=1024][N=320]
#define OFF_CVEC  (OFF_AMAT + N_*RNL)
#define OFF_LAT   (OFF_CVEC + RNL)               // fp32 lat [16384][320]
#define OFF_ACC   (OFF_LAT + (size_t)BT_*RNL)    // 5833280
#define OFF_BF16  (OFF_ACC + 16)                 // start of bf16 region (as ushort*)
// bf16 region: spikes_bf16 [16384][1024] then AmatT_bf16 [320][1024]
#define NEED_FP32_BYTES  ((size_t)(OFF_BF16) * 4)
#define NEED_BF16_BYTES  (NEED_FP32_BYTES + ((size_t)BT_*N_ + (size_t)RNL*N_) * 2)

__device__ __forceinline__ ushort f2bf(float f) {
    union { float f; unsigned u; } v; v.f = f;
    unsigned u = v.u;
    return (ushort)((u + 0x7fffu + ((u >> 16) & 1u)) >> 16);
}

__global__ void k_init(float* acc) {
    if (threadIdx.x < 2) acc[threadIdx.x] = 0.f;
}

// W_comb[row=r*64+n][h] = keep[r] * sum_c W_stitch[r][n][c] * W_U[r*32+c][h]
__global__ __launch_bounds__(256) void k_comb(const float* __restrict__ Wst,
                                              const float* __restrict__ Wu,
                                              const int* __restrict__ keep,
                                              float* __restrict__ Wcomb) {
    const int g = blockIdx.x * 256 + threadIdx.x;
    const int row = g >> 8, h = g & 255;
    const int r = row >> 6;
    const float* ws = Wst + (size_t)row * NC_;
    const float* wu = Wu + (size_t)(r * NC_) * H_ + h;
    float acc = 0.f;
#pragma unroll
    for (int c = 0; c < NC_; ++c) acc = fmaf(ws[c], wu[c * H_], acc);
    Wcomb[g] = keep[r] ? acc : 0.f;
}

__global__ void k_bcomb(const float* __restrict__ bst, const float* __restrict__ Wu,
                        const float* __restrict__ bu, const int* __restrict__ keep,
                        float* __restrict__ bcomb) {
    const int h = threadIdx.x;  // 256
    float acc = bu[h];
    for (int rc = 0; rc < RNC; ++rc)
        if (keep[rc >> 5]) acc = fmaf(bst[rc], Wu[(size_t)rc * H_ + h], acc);
    bcomb[h] = acc;
}

__global__ void k_cvec(const float* __restrict__ bcomb, const float* __restrict__ Wv,
                       const float* __restrict__ bv, float* __restrict__ cvec) {
    const int j = threadIdx.x;  // 320
    float acc = bv[j];
    for (int h = 0; h < H_; ++h) acc = fmaf(bcomb[h], Wv[(size_t)h * RNL + j], acc);
    cvec[j] = acc;
}

// fp32 tiled GEMM: C[M][N] = A[M][K] @ Bm[K][N] (+ bias if non-null)
__global__ __launch_bounds__(256) void gemm_bias(const float* __restrict__ A,
                                                 const float* __restrict__ Bm,
                                                 const float* __restrict__ bias,
                                                 float* __restrict__ C,
                                                 int M, int N, int K) {
    __shared__ float As[16][132];
    __shared__ float Bs[16][64];
    const int tid = threadIdx.x;
    const int bm = blockIdx.y * 128;
    const int bn = blockIdx.x * 64;
    const int tx = tid & 15, ty = tid >> 4;
    float acc[8][4];
#pragma unroll
    for (int i = 0; i < 8; ++i)
#pragma unroll
        for (int j = 0; j < 4; ++j) acc[i][j] = 0.f;
    for (int k0 = 0; k0 < K; k0 += 16) {
#pragma unroll
        for (int i = 0; i < 2; ++i) {
            const int idx = tid + i * 256;
            const int r = idx >> 2, kq = (idx & 3) << 2;
            const float4 v = *reinterpret_cast<const float4*>(
                A + (size_t)(bm + r) * K + k0 + kq);
            As[kq + 0][r] = v.x; As[kq + 1][r] = v.y;
            As[kq + 2][r] = v.z; As[kq + 3][r] = v.w;
        }
        {
            const int kr = tid >> 4, nq = (tid & 15) << 2;
            *reinterpret_cast<float4*>(&Bs[kr][nq]) =
                *reinterpret_cast<const float4*>(Bm + (size_t)(k0 + kr) * N + bn + nq);
        }
        __syncthreads();
#pragma unroll
        for (int k = 0; k < 16; ++k) {
            float a[8], b[4];
            *reinterpret_cast<float4*>(&a[0]) = *reinterpret_cast<const float4*>(&As[k][ty * 8]);
            *reinterpret_cast<float4*>(&a[4]) = *reinterpret_cast<const float4*>(&As[k][ty * 8 + 4]);
            *reinterpret_cast<float4*>(&b[0]) = *reinterpret_cast<const float4*>(&Bs[k][tx * 4]);
#pragma unroll
            for (int i = 0; i < 8; ++i)
#pragma unroll
                for (int j = 0; j < 4; ++j) acc[i][j] = fmaf(a[i], b[j], acc[i][j]);
        }
        __syncthreads();
    }
    float bv[4] = {0.f, 0.f, 0.f, 0.f};
    if (bias) {
        const float4 t = *reinterpret_cast<const float4*>(bias + bn + tx * 4);
        bv[0] = t.x; bv[1] = t.y; bv[2] = t.z; bv[3] = t.w;
    }
#pragma unroll
    for (int i = 0; i < 8; ++i) {
        float4 o;
        o.x = acc[i][0] + bv[0]; o.y = acc[i][1] + bv[1];
        o.z = acc[i][2] + bv[2]; o.w = acc[i][3] + bv[3];
        *reinterpret_cast<float4*>(C + (size_t)(bm + ty * 8 + i) * N + bn + tx * 4) = o;
    }
}

// spikes fp32 -> bf16 (RNE)
__global__ __launch_bounds__(256) void k_cast_spikes(const float* __restrict__ in,
                                                     ushort* __restrict__ out, int n4) {
    for (int i = blockIdx.x * 256 + threadIdx.x; i < n4; i += gridDim.x * 256) {
        const float4 v = reinterpret_cast<const float4*>(in)[i];
        ushort4 o;
        o.x = f2bf(v.x); o.y = f2bf(v.y); o.z = f2bf(v.z); o.w = f2bf(v.w);
        reinterpret_cast<ushort4*>(out)[i] = o;
    }
}

// AmatT_bf16[n][k] = bf16(Amat[k][n])   (320 x 1024)
__global__ __launch_bounds__(256) void k_castA(const float* __restrict__ Amat,
                                               ushort* __restrict__ AmatT) {
    const int g = blockIdx.x * 256 + threadIdx.x;  // 327680
    const int n = g >> 10, k = g & 1023;
    AmatT[g] = f2bf(Amat[(size_t)k * RNL + n]);
}

// lat[16384][320] = spikes_bf16[16384][1024] @ AmatT_bf16[320][1024]^T + cvec
// BM=128 BN=64 BK=64, 4 waves (2x2), per-wave 64x32 = 4x2 fragments of 16x16x32.
// Conservative staging: global->reg (short8) -> ds_write_b128, XOR-involution swizzle
// applied identically on write and read (rule #21). No inline asm, no global_load_lds.
__global__ __launch_bounds__(256) void gemm_mfma(const ushort* __restrict__ A,
                                                 const ushort* __restrict__ Bt,
                                                 const float* __restrict__ bias,
                                                 float* __restrict__ C) {
    __shared__ ushort As[128 * 64];  // row-major rows of 64 bf16, chunk-swizzled
    __shared__ ushort Bs[64 * 64];
    const int tid = threadIdx.x;
    const int bm = blockIdx.y * 128;
    const int bn = blockIdx.x * 64;
    const int w = tid >> 6;
    const int lane = tid & 63;
    const int wr = w >> 1, wc = w & 1;
    const int l15 = lane & 15, l16 = lane >> 4;

    f32x4 acc[4][2] = {};

    for (int kt = 0; kt < N_; kt += 64) {   // K = 1024
        // A tile: 128 rows x 8 chunks (16B each) = 1024 chunks, 4 per thread
        bf16x8 ra[4];
#pragma unroll
        for (int i = 0; i < 4; ++i) {
            const int ci = i * 256 + tid;
            const int row = ci >> 3, cp = ci & 7;
            ra[i] = *reinterpret_cast<const bf16x8*>(
                A + (size_t)(bm + row) * N_ + kt + cp * 8);
        }
        // B tile: 64 rows x 8 chunks = 512 chunks, 2 per thread
        bf16x8 rb[2];
#pragma unroll
        for (int i = 0; i < 2; ++i) {
            const int ci = i * 256 + tid;
            const int n = ci >> 3, cp = ci & 7;
            rb[i] = *reinterpret_cast<const bf16x8*>(
                Bt + (size_t)(bn + n) * N_ + kt + cp * 8);
        }
        __syncthreads();   // previous compute done before overwrite
#pragma unroll
        for (int i = 0; i < 4; ++i) {
            const int ci = i * 256 + tid;
            const int row = ci >> 3, cp = ci & 7;
            *reinterpret_cast<bf16x8*>(As + (row * 8 + (cp ^ (row & 7))) * 8) = ra[i];
        }
#pragma unroll
        for (int i = 0; i < 2; ++i) {
            const int ci = i * 256 + tid;
            const int n = ci >> 3, cp = ci & 7;
            *reinterpret_cast<bf16x8*>(Bs + (n * 8 + (cp ^ (n & 7))) * 8) = rb[i];
        }
        __syncthreads();
#pragma unroll
        for (int ks = 0; ks < 2; ++ks) {
            const int cb = ks * 4 + l16;  // 16B-chunk index in k for this lane
            bf16x8 af[4], bfr[2];
#pragma unroll
            for (int mi = 0; mi < 4; ++mi) {
                const int row = wr * 64 + mi * 16 + l15;
                af[mi] = *reinterpret_cast<const bf16x8*>(
                    As + (row * 8 + (cb ^ (row & 7))) * 8);
            }
#pragma unroll
            for (int ni = 0; ni < 2; ++ni) {
                const int n = wc * 32 + ni * 16 + l15;
                bfr[ni] = *reinterpret_cast<const bf16x8*>(
                    Bs + (n * 8 + (cb ^ (n & 7))) * 8);
            }
#pragma unroll
            for (int mi = 0; mi < 4; ++mi)
#pragma unroll
                for (int ni = 0; ni < 2; ++ni)
                    acc[mi][ni] = __builtin_amdgcn_mfma_f32_16x16x32_bf16(
                        af[mi], bfr[ni], acc[mi][ni], 0, 0, 0);
        }
    }
    // epilogue: D row=(lane>>4)*4+j, col=lane&15
#pragma unroll
    for (int ni = 0; ni < 2; ++ni) {
        const int n = bn + wc * 32 + ni * 16 + l15;
        const float bv = bias[n];
#pragma unroll
        for (int mi = 0; mi < 4; ++mi) {
#pragma unroll
            for (int j = 0; j < 4; ++j) {
                const int m = bm + wr * 64 + mi * 16 + l16 * 4 + j;
                C[(size_t)m * RNL + n] = acc[mi][ni][j] + bv;
            }
        }
    }
}

// preds + Poisson-NLL partial + fused reg (|diff(lat)|) partial.
__global__ __launch_bounds__(256) void k_pred(const float* __restrict__ lat,
                                              const float* __restrict__ Wd,
                                              const float* __restrict__ bd,
                                              const float* __restrict__ tgt,
                                              float* __restrict__ preds,
                                              float* __restrict__ acc) {
    __shared__ float ls[8 * RNL];
    const int tid = threadIdx.x;
    const int bt0 = blockIdx.x * 8;
    const float* latrow = lat + (size_t)bt0 * RNL;
    for (int i = tid; i < 8 * RNL; i += 256) ls[i] = latrow[i];
    __syncthreads();

    // reg part: |lat[row+1][j] - lat[row][j]| where (row % T_) != T_-1
    float rsum = 0.f;
    for (int i = tid; i < 8 * RNL; i += 256) {
        const int rr = i / RNL;
        const int row = bt0 + rr;
        if ((row & (T_ - 1)) != T_ - 1)
            rsum += fabsf(lat[(size_t)(row + 1) * RNL + (i - rr * RNL)] - ls[i]);
    }

    const int n0 = tid * 4;
    const int r = n0 >> 6;
    const int nn = n0 & 63;
    float4 wv[NL_];
#pragma unroll
    for (int l = 0; l < NL_; ++l)
        wv[l] = *reinterpret_cast<const float4*>(Wd + ((size_t)(r * NL_ + l)) * NP_ + nn);
    const float4 bb = *reinterpret_cast<const float4*>(bd + r * NP_ + nn);

    float lsum = 0.f;
#pragma unroll
    for (int tt = 0; tt < 8; ++tt) {
        float p0 = bb.x, p1 = bb.y, p2 = bb.z, p3 = bb.w;
        const float* lr = &ls[tt * RNL + r * NL_];
#pragma unroll
        for (int l = 0; l < NL_; ++l) {
            const float lv = lr[l];
            p0 = fmaf(lv, wv[l].x, p0); p1 = fmaf(lv, wv[l].y, p1);
            p2 = fmaf(lv, wv[l].z, p2); p3 = fmaf(lv, wv[l].w, p3);
        }
        const size_t idx = (size_t)(bt0 + tt) * N_ + n0;
        const float4 tg = *reinterpret_cast<const float4*>(tgt + idx);
        float4 o; o.x = p0; o.y = p1; o.z = p2; o.w = p3;
        *reinterpret_cast<float4*>(preds + idx) = o;
        lsum += (__expf(p0) - tg.x * p0) + (__expf(p1) - tg.y * p1)
              + (__expf(p2) - tg.z * p2) + (__expf(p3) - tg.w * p3);
    }
#pragma unroll
    for (int off = 32; off; off >>= 1) {
        lsum += __shfl_down(lsum, off);
        rsum += __shfl_down(rsum, off);
    }
    __shared__ float red[8];
    if ((tid & 63) == 0) { red[tid >> 6] = lsum; red[4 + (tid >> 6)] = rsum; }
    __syncthreads();
    if (tid == 0) {
        atomicAdd(acc, red[0] + red[1] + red[2] + red[3]);
        atomicAdd(acc + 1, red[4] + red[5] + red[6] + red[7]);
    }
}

__global__ void k_fin(const float* __restrict__ acc, float* __restrict__ out) {
    if (threadIdx.x == 0) {
        out[0] = acc[0] * (1.0f / ((float)BT_ * N_));
        out[1] = acc[1] * (0.1f / ((float)B_ * (T_ - 1) * RNL));
    }
}

extern "C" void kernel_launch(void* const* d_in, const int* in_sizes, int n_in,
                              void* d_out, int out_size, void* d_ws, size_t ws_size,
                              hipStream_t stream) {
    const float* spikes = (const float*)d_in[0];
    const int*   keep   = (const int*)d_in[2];
    const float* Wst    = (const float*)d_in[3];
    const float* bst    = (const float*)d_in[4];
    const float* Wu     = (const float*)d_in[5];
    const float* bu     = (const float*)d_in[6];
    const float* Wv     = (const float*)d_in[7];
    const float* bv     = (const float*)d_in[8];
    const float* Wd     = (const float*)d_in[9];
    const float* bd     = (const float*)d_in[10];
    float* out = (float*)d_out;
    float* ws  = (float*)d_ws;

    float* Wcomb = ws + OFF_WCOMB;
    float* bcomb = ws + OFF_BCOMB;
    float* Amat  = ws + OFF_AMAT;
    float* cvec  = ws + OFF_CVEC;
    float* lat   = ws + OFF_LAT;
    float* acc   = ws + OFF_ACC;
    ushort* spikes_bf = (ushort*)(ws + OFF_BF16);
    ushort* AmatT_bf  = spikes_bf + (size_t)BT_ * N_;

    // ws_size is constant across calls -> deterministic path choice (graph-safe).
    const bool use_bf16 = ws_size >= NEED_BF16_BYTES;

    k_init<<<1, 64, 0, stream>>>(acc);
    k_comb<<<(N_ * H_) / 256, 256, 0, stream>>>(Wst, Wu, keep, Wcomb);
    k_bcomb<<<1, 256, 0, stream>>>(bst, Wu, bu, keep, bcomb);
    k_cvec<<<1, RNL, 0, stream>>>(bcomb, Wv, bv, cvec);
    // Amat = Wcomb @ Wv  (1024x320, K=256), fp32
    gemm_bias<<<dim3(RNL / 64, N_ / 128), 256, 0, stream>>>(Wcomb, Wv, nullptr, Amat,
                                                            N_, RNL, H_);
    if (use_bf16) {
        k_castA<<<(RNL * N_) / 256, 256, 0, stream>>>(Amat, AmatT_bf);
        k_cast_spikes<<<2048, 256, 0, stream>>>(spikes, spikes_bf, (BT_ * N_) / 4);
        // lat = spikes_bf @ AmatT_bf^T + cvec  (16384x320, K=1024), bf16 MFMA
        gemm_mfma<<<dim3(RNL / 64, BT_ / 128), 256, 0, stream>>>(spikes_bf, AmatT_bf,
                                                                 cvec, lat);
    } else {
        // fallback: proven fp32 path (fits in 23.3 MB)
        gemm_bias<<<dim3(RNL / 64, BT_ / 128), 256, 0, stream>>>(spikes, Amat, cvec, lat,
                                                                 BT_, RNL, N_);
    }
    k_pred<<<BT_ / 8, 256, 0, stream>>>(lat, Wd, bd, spikes, out + 2, acc);
    k_fin<<<1, 64, 0, stream>>>(acc, out);
}

// Round 6
// 269.389 us; speedup vs baseline: 1.6469x; 1.2336x over previous
//
#include <hip/hip_runtime.h>
#include <hip/hip_bf16.h>

// Problem dims (fixed)
#define B_   16
#define T_   1024
#define R_   16
#define NP_  64
#define N_   1024      // R_*NP_
#define NL_  20
#define NC_  32
#define H_   256
#define RNL  320       // R_*NL_
#define RNC  512       // R_*NC_
#define BT_  (B_*T_)   // 16384

typedef __attribute__((ext_vector_type(8))) short bf16x8;
typedef __attribute__((ext_vector_type(4))) float f32x4;

// ws layout (float offsets)
#define OFF_WCOMB 0
#define OFF_BCOMB (OFF_WCOMB + N_*H_)            // 262144
#define OFF_AMAT  (OFF_BCOMB + H_)
#define OFF_CVEC  (OFF_AMAT + N_*RNL)
#define OFF_LAT   (OFF_CVEC + RNL)               // fp32 lat [16384][320]
#define OFF_ACC   (OFF_LAT + (size_t)BT_*RNL)
#define OFF_BF16  (OFF_ACC + 16)                 // bf16 region (as ushort*)
#define NEED_FP32_BYTES  ((size_t)(OFF_BF16) * 4)
#define NEED_BF16_BYTES  (NEED_FP32_BYTES + ((size_t)BT_*N_ + (size_t)RNL*N_) * 2)

__device__ __forceinline__ ushort f2bf(float f) {
    union { float f; unsigned u; } v; v.f = f;
    unsigned u = v.u;
    return (ushort)((u + 0x7fffu + ((u >> 16) & 1u)) >> 16);
}

// W_comb[row][h]; block 0 also zeroes the accumulators (k_init folded in).
__global__ __launch_bounds__(256) void k_comb(const float* __restrict__ Wst,
                                              const float* __restrict__ Wu,
                                              const int* __restrict__ keep,
                                              float* __restrict__ Wcomb,
                                              float* __restrict__ acc0) {
    if (blockIdx.x == 0 && threadIdx.x < 2) acc0[threadIdx.x] = 0.f;
    const int g = blockIdx.x * 256 + threadIdx.x;
    const int row = g >> 8, h = g & 255;
    const int r = row >> 6;
    const float* ws = Wst + (size_t)row * NC_;
    const float* wu = Wu + (size_t)(r * NC_) * H_ + h;
    float acc = 0.f;
#pragma unroll
    for (int c = 0; c < NC_; ++c) acc = fmaf(ws[c], wu[c * H_], acc);
    Wcomb[g] = keep[r] ? acc : 0.f;
}

// Parallel: one block per h (256 blocks); 512-term reduction split over 256 threads.
__global__ __launch_bounds__(256) void k_bcomb(const float* __restrict__ bst,
                                               const float* __restrict__ Wu,
                                               const float* __restrict__ bu,
                                               const int* __restrict__ keep,
                                               float* __restrict__ bcomb) {
    const int h = blockIdx.x;
    const int t = threadIdx.x;
    float acc = 0.f;
#pragma unroll
    for (int i = 0; i < 2; ++i) {
        const int rc = t + i * 256;
        if (keep[rc >> 5]) acc = fmaf(bst[rc], Wu[(size_t)rc * H_ + h], acc);
    }
#pragma unroll
    for (int off = 32; off; off >>= 1) acc += __shfl_down(acc, off);
    __shared__ float red[4];
    if ((t & 63) == 0) red[t >> 6] = acc;
    __syncthreads();
    if (t == 0) bcomb[h] = bu[h] + red[0] + red[1] + red[2] + red[3];
}

// Parallel: one block per j (320 blocks); 256-term reduction over h.
__global__ __launch_bounds__(256) void k_cvec(const float* __restrict__ bcomb,
                                              const float* __restrict__ Wv,
                                              const float* __restrict__ bv,
                                              float* __restrict__ cvec) {
    const int j = blockIdx.x;
    const int t = threadIdx.x;  // h
    float acc = bcomb[t] * Wv[(size_t)t * RNL + j];
#pragma unroll
    for (int off = 32; off; off >>= 1) acc += __shfl_down(acc, off);
    __shared__ float red[4];
    if ((t & 63) == 0) red[t >> 6] = acc;
    __syncthreads();
    if (t == 0) cvec[j] = bv[j] + red[0] + red[1] + red[2] + red[3];
}

// fp32 tiled GEMM: C[M][N] = A[M][K] @ Bm[K][N] (no bias; used for Amat + fallback)
__global__ __launch_bounds__(256) void gemm_bias(const float* __restrict__ A,
                                                 const float* __restrict__ Bm,
                                                 float* __restrict__ C,
                                                 int M, int N, int K) {
    __shared__ float As[16][132];
    __shared__ float Bs[16][64];
    const int tid = threadIdx.x;
    const int bm = blockIdx.y * 128;
    const int bn = blockIdx.x * 64;
    const int tx = tid & 15, ty = tid >> 4;
    float acc[8][4];
#pragma unroll
    for (int i = 0; i < 8; ++i)
#pragma unroll
        for (int j = 0; j < 4; ++j) acc[i][j] = 0.f;
    for (int k0 = 0; k0 < K; k0 += 16) {
#pragma unroll
        for (int i = 0; i < 2; ++i) {
            const int idx = tid + i * 256;
            const int r = idx >> 2, kq = (idx & 3) << 2;
            const float4 v = *reinterpret_cast<const float4*>(
                A + (size_t)(bm + r) * K + k0 + kq);
            As[kq + 0][r] = v.x; As[kq + 1][r] = v.y;
            As[kq + 2][r] = v.z; As[kq + 3][r] = v.w;
        }
        {
            const int kr = tid >> 4, nq = (tid & 15) << 2;
            *reinterpret_cast<float4*>(&Bs[kr][nq]) =
                *reinterpret_cast<const float4*>(Bm + (size_t)(k0 + kr) * N + bn + nq);
        }
        __syncthreads();
#pragma unroll
        for (int k = 0; k < 16; ++k) {
            float a[8], b[4];
            *reinterpret_cast<float4*>(&a[0]) = *reinterpret_cast<const float4*>(&As[k][ty * 8]);
            *reinterpret_cast<float4*>(&a[4]) = *reinterpret_cast<const float4*>(&As[k][ty * 8 + 4]);
            *reinterpret_cast<float4*>(&b[0]) = *reinterpret_cast<const float4*>(&Bs[k][tx * 4]);
#pragma unroll
            for (int i = 0; i < 8; ++i)
#pragma unroll
                for (int j = 0; j < 4; ++j) acc[i][j] = fmaf(a[i], b[j], acc[i][j]);
        }
        __syncthreads();
    }
#pragma unroll
    for (int i = 0; i < 8; ++i) {
        float4 o;
        o.x = acc[i][0]; o.y = acc[i][1]; o.z = acc[i][2]; o.w = acc[i][3];
        *reinterpret_cast<float4*>(C + (size_t)(bm + ty * 8 + i) * N + bn + tx * 4) = o;
    }
}

// spikes fp32 -> bf16 (RNE)
__global__ __launch_bounds__(256) void k_cast_spikes(const float* __restrict__ in,
                                                     ushort* __restrict__ out, int n4) {
    for (int i = blockIdx.x * 256 + threadIdx.x; i < n4; i += gridDim.x * 256) {
        const float4 v = reinterpret_cast<const float4*>(in)[i];
        ushort4 o;
        o.x = f2bf(v.x); o.y = f2bf(v.y); o.z = f2bf(v.z); o.w = f2bf(v.w);
        reinterpret_cast<ushort4*>(out)[i] = o;
    }
}

// AmatT_bf16[n][k] = bf16(Amat[k][n])   (320 x 1024)
__global__ __launch_bounds__(256) void k_castA(const float* __restrict__ Amat,
                                               ushort* __restrict__ AmatT) {
    const int g = blockIdx.x * 256 + threadIdx.x;  // 327680
    const int n = g >> 10, k = g & 1023;
    AmatT[g] = f2bf(Amat[(size_t)k * RNL + n]);
}

// lat = spikes_bf @ AmatT_bf^T + cvec. BM=128 BN=64 BK=64, 4 waves (2x2).
// Reg-staged global->LDS with both-sides XOR-involution swizzle (rule #21).
__global__ __launch_bounds__(256) void gemm_mfma(const ushort* __restrict__ A,
                                                 const ushort* __restrict__ Bt,
                                                 const float* __restrict__ bias,
                                                 float* __restrict__ C) {
    __shared__ ushort As[128 * 64];
    __shared__ ushort Bs[64 * 64];
    const int tid = threadIdx.x;
    const int bm = blockIdx.y * 128;
    const int bn = blockIdx.x * 64;
    const int w = tid >> 6;
    const int lane = tid & 63;
    const int wr = w >> 1, wc = w & 1;
    const int l15 = lane & 15, l16 = lane >> 4;

    f32x4 acc[4][2] = {};

    for (int kt = 0; kt < N_; kt += 64) {   // K = 1024
        bf16x8 ra[4];
#pragma unroll
        for (int i = 0; i < 4; ++i) {
            const int ci = i * 256 + tid;
            const int row = ci >> 3, cp = ci & 7;
            ra[i] = *reinterpret_cast<const bf16x8*>(
                A + (size_t)(bm + row) * N_ + kt + cp * 8);
        }
        bf16x8 rb[2];
#pragma unroll
        for (int i = 0; i < 2; ++i) {
            const int ci = i * 256 + tid;
            const int n = ci >> 3, cp = ci & 7;
            rb[i] = *reinterpret_cast<const bf16x8*>(
                Bt + (size_t)(bn + n) * N_ + kt + cp * 8);
        }
        __syncthreads();
#pragma unroll
        for (int i = 0; i < 4; ++i) {
            const int ci = i * 256 + tid;
            const int row = ci >> 3, cp = ci & 7;
            *reinterpret_cast<bf16x8*>(As + (row * 8 + (cp ^ (row & 7))) * 8) = ra[i];
        }
#pragma unroll
        for (int i = 0; i < 2; ++i) {
            const int ci = i * 256 + tid;
            const int n = ci >> 3, cp = ci & 7;
            *reinterpret_cast<bf16x8*>(Bs + (n * 8 + (cp ^ (n & 7))) * 8) = rb[i];
        }
        __syncthreads();
#pragma unroll
        for (int ks = 0; ks < 2; ++ks) {
            const int cb = ks * 4 + l16;
            bf16x8 af[4], bfr[2];
#pragma unroll
            for (int mi = 0; mi < 4; ++mi) {
                const int row = wr * 64 + mi * 16 + l15;
                af[mi] = *reinterpret_cast<const bf16x8*>(
                    As + (row * 8 + (cb ^ (row & 7))) * 8);
            }
#pragma unroll
            for (int ni = 0; ni < 2; ++ni) {
                const int n = wc * 32 + ni * 16 + l15;
                bfr[ni] = *reinterpret_cast<const bf16x8*>(
                    Bs + (n * 8 + (cb ^ (n & 7))) * 8);
            }
#pragma unroll
            for (int mi = 0; mi < 4; ++mi)
#pragma unroll
                for (int ni = 0; ni < 2; ++ni)
                    acc[mi][ni] = __builtin_amdgcn_mfma_f32_16x16x32_bf16(
                        af[mi], bfr[ni], acc[mi][ni], 0, 0, 0);
        }
    }
#pragma unroll
    for (int ni = 0; ni < 2; ++ni) {
        const int n = bn + wc * 32 + ni * 16 + l15;
        const float bv = bias[n];
#pragma unroll
        for (int mi = 0; mi < 4; ++mi) {
#pragma unroll
            for (int j = 0; j < 4; ++j) {
                const int m = bm + wr * 64 + mi * 16 + l16 * 4 + j;
                C[(size_t)m * RNL + n] = acc[mi][ni][j] + bv;
            }
        }
    }
}

// preds + Poisson-NLL partial + fused reg (|diff(lat)|) partial.
__global__ __launch_bounds__(256) void k_pred(const float* __restrict__ lat,
                                              const float* __restrict__ Wd,
                                              const float* __restrict__ bd,
                                              const float* __restrict__ tgt,
                                              float* __restrict__ preds,
                                              float* __restrict__ acc) {
    __shared__ float ls[8 * RNL];
    const int tid = threadIdx.x;
    const int bt0 = blockIdx.x * 8;
    const float* latrow = lat + (size_t)bt0 * RNL;
    for (int i = tid; i < 8 * RNL; i += 256) ls[i] = latrow[i];
    __syncthreads();

    // reg part: rows rr<7 fully in LDS; boundary row rr==7 reads next row from global.
    float rsum = 0.f;
    for (int i = tid; i < 7 * RNL; i += 256) rsum += fabsf(ls[i + RNL] - ls[i]);
    if ((bt0 & (T_ - 1)) != T_ - 8) {  // row bt0+7 is not last-in-trial
        for (int i = tid; i < RNL; i += 256)
            rsum += fabsf(lat[(size_t)(bt0 + 8) * RNL + i] - ls[7 * RNL + i]);
    }

    const int n0 = tid * 4;
    const int r = n0 >> 6;
    const int nn = n0 & 63;
    float4 wv[NL_];
#pragma unroll
    for (int l = 0; l < NL_; ++l)
        wv[l] = *reinterpret_cast<const float4*>(Wd + ((size_t)(r * NL_ + l)) * NP_ + nn);
    const float4 bb = *reinterpret_cast<const float4*>(bd + r * NP_ + nn);

    float lsum = 0.f;
#pragma unroll
    for (int tt = 0; tt < 8; ++tt) {
        float p0 = bb.x, p1 = bb.y, p2 = bb.z, p3 = bb.w;
        const float* lr = &ls[tt * RNL + r * NL_];
#pragma unroll
        for (int l = 0; l < NL_; ++l) {
            const float lv = lr[l];
            p0 = fmaf(lv, wv[l].x, p0); p1 = fmaf(lv, wv[l].y, p1);
            p2 = fmaf(lv, wv[l].z, p2); p3 = fmaf(lv, wv[l].w, p3);
        }
        const size_t idx = (size_t)(bt0 + tt) * N_ + n0;
        const float4 tg = *reinterpret_cast<const float4*>(tgt + idx);
        float4 o; o.x = p0; o.y = p1; o.z = p2; o.w = p3;
        *reinterpret_cast<float4*>(preds + idx) = o;
        lsum += (__expf(p0) - tg.x * p0) + (__expf(p1) - tg.y * p1)
              + (__expf(p2) - tg.z * p2) + (__expf(p3) - tg.w * p3);
    }
#pragma unroll
    for (int off = 32; off; off >>= 1) {
        lsum += __shfl_down(lsum, off);
        rsum += __shfl_down(rsum, off);
    }
    __shared__ float red[8];
    if ((tid & 63) == 0) { red[tid >> 6] = lsum; red[4 + (tid >> 6)] = rsum; }
    __syncthreads();
    if (tid == 0) {
        atomicAdd(acc, red[0] + red[1] + red[2] + red[3]);
        atomicAdd(acc + 1, red[4] + red[5] + red[6] + red[7]);
    }
}

// broadcast-add cvec over lat rows (fallback path only)
__global__ __launch_bounds__(256) void k_addc(float* __restrict__ lat,
                                              const float* __restrict__ cvec) {
    const int total = BT_ * RNL;
    for (int i = blockIdx.x * 256 + threadIdx.x; i < total; i += gridDim.x * 256)
        lat[i] += cvec[i % RNL];
}

__global__ void k_fin(const float* __restrict__ acc, float* __restrict__ out) {
    if (threadIdx.x == 0) {
        out[0] = acc[0] * (1.0f / ((float)BT_ * N_));
        out[1] = acc[1] * (0.1f / ((float)B_ * (T_ - 1) * RNL));
    }
}

extern "C" void kernel_launch(void* const* d_in, const int* in_sizes, int n_in,
                              void* d_out, int out_size, void* d_ws, size_t ws_size,
                              hipStream_t stream) {
    const float* spikes = (const float*)d_in[0];
    const int*   keep   = (const int*)d_in[2];
    const float* Wst    = (const float*)d_in[3];
    const float* bst    = (const float*)d_in[4];
    const float* Wu     = (const float*)d_in[5];
    const float* bu     = (const float*)d_in[6];
    const float* Wv     = (const float*)d_in[7];
    const float* bv     = (const float*)d_in[8];
    const float* Wd     = (const float*)d_in[9];
    const float* bd     = (const float*)d_in[10];
    float* out = (float*)d_out;
    float* ws  = (float*)d_ws;

    float* Wcomb = ws + OFF_WCOMB;
    float* bcomb = ws + OFF_BCOMB;
    float* Amat  = ws + OFF_AMAT;
    float* cvec  = ws + OFF_CVEC;
    float* lat   = ws + OFF_LAT;
    float* acc   = ws + OFF_ACC;
    ushort* spikes_bf = (ushort*)(ws + OFF_BF16);
    ushort* AmatT_bf  = spikes_bf + (size_t)BT_ * N_;

    const bool use_bf16 = ws_size >= NEED_BF16_BYTES;

    k_comb<<<(N_ * H_) / 256, 256, 0, stream>>>(Wst, Wu, keep, Wcomb, acc);
    k_bcomb<<<H_, 256, 0, stream>>>(bst, Wu, bu, keep, bcomb);
    k_cvec<<<RNL, 256, 0, stream>>>(bcomb, Wv, bv, cvec);
    gemm_bias<<<dim3(RNL / 64, N_ / 128), 256, 0, stream>>>(Wcomb, Wv, Amat, N_, RNL, H_);
    if (use_bf16) {
        k_castA<<<(RNL * N_) / 256, 256, 0, stream>>>(Amat, AmatT_bf);
        k_cast_spikes<<<2048, 256, 0, stream>>>(spikes, spikes_bf, (BT_ * N_) / 4);
        gemm_mfma<<<dim3(RNL / 64, BT_ / 128), 256, 0, stream>>>(spikes_bf, AmatT_bf,
                                                                 cvec, lat);
    } else {
        // fallback: fp32 GEMM then broadcast-add cvec
        gemm_bias<<<dim3(RNL / 64, BT_ / 128), 256, 0, stream>>>(spikes, Amat, lat,
                                                                 BT_, RNL, N_);
        k_addc<<<2048, 256, 0, stream>>>(lat, cvec);
    }
    k_pred<<<BT_ / 8, 256, 0, stream>>>(lat, Wd, bd, spikes, out + 2, acc);
    k_fin<<<1, 64, 0, stream>>>(acc, out);
}